// Round 6
// baseline (8234.447 us; speedup 1.0000x reference)
//
#include <hip/hip_runtime.h>
#include <hip/hip_bf16.h>

typedef __attribute__((ext_vector_type(8))) short short8;
typedef __attribute__((ext_vector_type(4))) float floatx4;
typedef __attribute__((ext_vector_type(4))) unsigned int uintx4;
typedef unsigned int u32;

#define Bb 32
#define Ss 2048
#define Ii 256
#define Hh 256

// ws layout:
//   [4096, 53248)   data: u32 data[3][32][128] — value-validated h exchange, slot = t%3
//                   word = packed bf16 pair | 0x4000 (written, lo bit14) | parity<<30 (hi bit14)
//                   (|h|<=1.0 => bf16 bit14 always 0 => both bits free; 0xAAAAAAAA and
//                    0x00000000 poison both fail the check)
//   [65536, ...)    gx: bf16 pre-activation fragments (proven layout)
#define DATA_OFF 4096
#define GX_OFF   65536
// container-safety: ONE global timeout budget (~0.2s), then permanent dead-latch
#define RETRY_DEAD (1u << 17)

__device__ __forceinline__ unsigned short f2bf(float f) {
    unsigned int u = __float_as_uint(f);
    u += 0x7fffu + ((u >> 16) & 1u);   // RNE
    return (unsigned short)(u >> 16);
}
__device__ __forceinline__ float bf2f_lo(u32 w) { return __uint_as_float(w << 16); }
__device__ __forceinline__ float bf2f_hi(u32 w) { return __uint_as_float(w & 0xffff0000u); }

__device__ __forceinline__ float fast_sigmoid(float x) {
    return __builtin_amdgcn_rcpf(1.0f + __expf(-x));
}
__device__ __forceinline__ float fast_tanh(float x) {
    return 1.0f - 2.0f * __builtin_amdgcn_rcpf(__expf(2.0f * x) + 1.0f);
}

// counted wait + scheduler fence (rule #18): nothing reading asm-loaded regs may
// hoist above this point
#define WAITV(N) do { asm volatile("s_waitcnt vmcnt(" #N ")" ::: "memory"); \
                      __builtin_amdgcn_sched_barrier(0); } while (0)

// issue one 8x dwordx4 poll bundle (sc0 sc1 = MALL-coherent, proven) — NO wait
#define ISSUE8(V, PD)                                                        \
    asm volatile("global_load_dwordx4 %0, %8, off sc0 sc1\n\t"               \
                 "global_load_dwordx4 %1, %8, off offset:64 sc0 sc1\n\t"     \
                 "global_load_dwordx4 %2, %8, off offset:128 sc0 sc1\n\t"    \
                 "global_load_dwordx4 %3, %8, off offset:192 sc0 sc1\n\t"    \
                 "global_load_dwordx4 %4, %8, off offset:256 sc0 sc1\n\t"    \
                 "global_load_dwordx4 %5, %8, off offset:320 sc0 sc1\n\t"    \
                 "global_load_dwordx4 %6, %8, off offset:384 sc0 sc1\n\t"    \
                 "global_load_dwordx4 %7, %8, off offset:448 sc0 sc1"        \
                 : "=&v"(V[0]), "=&v"(V[1]), "=&v"(V[2]), "=&v"(V[3]),       \
                   "=&v"(V[4]), "=&v"(V[5]), "=&v"(V[6]), "=&v"(V[7])        \
                 : "v"(PD) : "memory")

// issue the next step's gx fragment loads (plain: MALL-cacheable, read-once) — NO wait
#define ISSUEG(GA, GB, P)                                                    \
    asm volatile("global_load_dwordx4 %0, %2, off\n\t"                       \
                 "global_load_dwordx4 %1, %2, off offset:16"                 \
                 : "=&v"(GA), "=&v"(GB) : "v"(P) : "memory")

// ---------------- Phase 1: gx[t] = x_t @ Wx_all + b_all (byte-identical, proven)
__global__ __launch_bounds__(256, 2)
void lstm_gx_kernel(const float* __restrict__ x,
                    const float* __restrict__ Wf, const float* __restrict__ bfp,
                    const float* __restrict__ Wi, const float* __restrict__ bip,
                    const float* __restrict__ Wc, const float* __restrict__ bcp,
                    const float* __restrict__ Wo, const float* __restrict__ bop,
                    u32* __restrict__ gx)
{
    const int tid = threadIdx.x, wave = tid >> 6, lane = tid & 63;
    const int ln = lane & 15, lg = lane >> 4;
    const int combo = blockIdx.x & 7;
    const int tbase = (blockIdx.x >> 3) * 8;
    const int wg = ((combo & 1) << 2) + wave;
    const int chalf = (combo >> 1) & 1, mtile = combo >> 2;
    const int j0 = wg * 32 + chalf * 16, r0 = mtile * 16;
    const int wv = wg * 4 + chalf * 2 + mtile;

    const float* Wg[4] = {Wf, Wi, Wc, Wo};
    const float* bg[4] = {bfp, bip, bcp, bop};
    float bias[4];
#pragma unroll
    for (int g = 0; g < 4; ++g) bias[g] = bg[g][j0 + ln];

    short8 Bf[4][8];
#pragma unroll
    for (int g = 0; g < 4; ++g)
#pragma unroll
        for (int ks = 0; ks < 8; ++ks) {
            short8 v;
#pragma unroll
            for (int i = 0; i < 8; ++i) {
                int k = 256 + 32 * ks + 8 * lg + i;
                v[i] = (short)f2bf(Wg[g][k * Hh + (j0 + ln)]);
            }
            Bf[g][ks] = v;
        }

    for (int it = 0; it < 8; ++it) {
        int t = tbase + it;
        short8 xf[8];
#pragma unroll
        for (int ks = 0; ks < 8; ++ks) {
            const float* px = x + (r0 + ln) * (Ss * Ii) + t * Ii + 32 * ks + 8 * lg;
            floatx4 a = *(const floatx4*)px;
            floatx4 b = *(const floatx4*)(px + 4);
            short8 v;
#pragma unroll
            for (int q = 0; q < 4; ++q) { v[q] = (short)f2bf(a[q]); v[4 + q] = (short)f2bf(b[q]); }
            xf[ks] = v;
        }
        floatx4 acc[4];
#pragma unroll
        for (int g = 0; g < 4; ++g) acc[g] = (floatx4){0.f, 0.f, 0.f, 0.f};
#pragma unroll
        for (int ks = 0; ks < 8; ++ks)
#pragma unroll
            for (int g = 0; g < 4; ++g)
                acc[g] = __builtin_amdgcn_mfma_f32_16x16x32_bf16(xf[ks], Bf[g][ks], acc[g], 0, 0, 0);

        u32 o[8];
#pragma unroll
        for (int g = 0; g < 4; ++g)
#pragma unroll
            for (int rp = 0; rp < 2; ++rp) {
                float v0 = acc[g][2 * rp] + bias[g];
                float v1 = acc[g][2 * rp + 1] + bias[g];
                o[g * 2 + rp] = (u32)f2bf(v0) | ((u32)f2bf(v1) << 16);
            }
        u32* dst = gx + ((size_t)(t * 32 + wv) * 64 + lane) * 8;
        ((uintx4*)dst)[0] = (uintx4){o[0], o[1], o[2], o[3]};
        ((uintx4*)dst)[1] = (uintx4){o[4], o[5], o[6], o[7]};
    }
}

// ---------------- Phase 2: round-3 protocol + counted-vmcnt ping-pong polling.
// Per-step VMEM issue order (static): pub(4) out(4) A(8) B(8) G(2)
//   wait1 vmcnt(10): A inspectable; B,G stay in flight
//   wait2 vmcnt(2):  B inspectable; G stays in flight
//   reissue loop:    vmcnt(8) ping-pong, sampling period ~RT/2
//   body: vmcnt(0) before consuming G regs (full drain => counting never affects
//   correctness; value-validation covers data regs under any miscount)
__global__ __launch_bounds__(256, 1)
void lstm_rec11(const float* __restrict__ h0,
                const float* __restrict__ c0,
                const float* __restrict__ Wf,
                const float* __restrict__ Wi,
                const float* __restrict__ Wc,
                const float* __restrict__ Wo,
                float* __restrict__ out,
                u32* data, const u32* __restrict__ gx)
{
    const int wg = blockIdx.x;
    const int tid = threadIdx.x;
    const int wave = tid >> 6, lane = tid & 63;
    const int mt = wave & 1, chalf = wave >> 1;   // batch-half, col-block
    const int ln = lane & 15, lg = lane >> 4;
    const int j0 = wg * 32 + chalf * 16;
    const int j = j0 + ln;
    const int wv = wg * 4 + chalf * 2 + mt;       // gx fragment slot (matches writer)

    const float* Wg[4] = {Wf, Wi, Wc, Wo};
    short8 Bfrag[4][8];                            // h-part weights, full K=256
#pragma unroll
    for (int g = 0; g < 4; ++g)
#pragma unroll
        for (int ks = 0; ks < 8; ++ks) {
            short8 v;
#pragma unroll
            for (int i = 0; i < 8; ++i) {
                int k = 32 * ks + 8 * lg + i;
                v[i] = (short)f2bf(Wg[g][k * Hh + j]);
            }
            Bfrag[g][ks] = v;
        }

    float cst[4], hl[4];
#pragma unroll
    for (int r = 0; r < 4; ++r) {
        cst[r] = c0[(16 * mt + 4 * lg + r) * Hh + j];
        hl[r] = 0.0f;
    }

    uintx4 dvA[8], dvB[8];
    uintx4 g0, g1;
    u32 itb = 0, dead = 0;

    // parity-validity check over one 8-bundle; wave-uniform verdict
    auto chk = [&](const uintx4 v[8], u32 want) -> bool {
        u32 bad = 0;
#pragma unroll
        for (int ks = 0; ks < 8; ++ks) {
            bad |= (v[ks].x & 0x40004000u) ^ want;
            bad |= (v[ks].y & 0x40004000u) ^ want;
            bad |= (v[ks].z & 0x40004000u) ^ want;
            bad |= (v[ks].w & 0x40004000u) ^ want;
        }
        return !__any((int)(bad != 0));
    };

    // gates + state update (registers only, byte-identical math to round 3)
    auto gates = [&](floatx4 (&acc)[4], float (&hnew)[4]) {
#pragma unroll
        for (int r = 0; r < 4; ++r) {
            float fg = fast_sigmoid(acc[0][r]);
            float ig = fast_sigmoid(acc[1][r]);
            float cd = fast_tanh(acc[2][r]);
            float og = fast_sigmoid(acc[3][r]);
            float c  = cst[r] * fg + ig * cd;
            cst[r] = c;
            hnew[r] = og * fast_tanh(c);
            hl[r] = hnew[r];
        }
    };

    auto run_mfma = [&](short8 (&afr)[8], floatx4 (&acc)[4]) {
#pragma unroll
        for (int ks = 0; ks < 8; ++ks)
#pragma unroll
            for (int g = 0; g < 4; ++g)
                acc[g] = __builtin_amdgcn_mfma_f32_16x16x32_bf16(afr[ks], Bfrag[g][ks], acc[g], 0, 0, 0);
    };

    int sr = 0, sw = 0;

    // shared step tail: publish h_t -> slot sw, out stores, issue next polls + next gx.
    // VMEM order pub,out,A,B,G is what the counted waits assume.
    auto tail = [&](int t, const float hnew[4]) {
        const u32 tb = 0x4000u | ((u32)(t & 1) << 30);
        u32 wrd[4];
#pragma unroll
        for (int r = 0; r < 4; ++r) {
            float partner = __shfl_xor(hnew[r], 1);
            wrd[r] = ((u32)f2bf(hnew[r]) | ((u32)f2bf(partner) << 16)) | tb;  // even lanes valid
        }
        u32* pw = data + sw * 4096 + (16 * mt + 4 * lg) * 128 + (j >> 1);
        if ((ln & 1) == 0) {
            asm volatile("global_store_dword %4, %0, off sc0 sc1\n\t"
                         "global_store_dword %4, %1, off offset:512 sc0 sc1\n\t"
                         "global_store_dword %4, %2, off offset:1024 sc0 sc1\n\t"
                         "global_store_dword %4, %3, off offset:1536 sc0 sc1"
                         :: "v"(wrd[0]), "v"(wrd[1]), "v"(wrd[2]), "v"(wrd[3]), "v"(pw)
                         : "memory");
        }
#pragma unroll
        for (int r = 0; r < 4; ++r)
            out[(16 * mt + 4 * lg + r) * (Ss * Hh) + t * Hh + j] = hnew[r];
        const u32* pdn = data + sw * 4096 + (16 * mt + ln) * 128 + 4 * lg;
        ISSUE8(dvA, pdn);
        ISSUE8(dvB, pdn);
        int tg = (t + 1 < Ss) ? (t + 1) : (Ss - 1);     // clamp: never read past gx end
        const u32* pg = gx + ((size_t)(tg * 32 + wv) * 64 + lane) * 8;
        ISSUEG(g0, g1, pg);
        sr = sw; sw = (sw == 2) ? 0 : sw + 1;
    };

    // ---- step 0: A-fragments straight from h0 (global, fully available — no exchange)
    {
        short8 a0[8];
        const float* hr = h0 + (16 * mt + ln) * Hh;
#pragma unroll
        for (int ks = 0; ks < 8; ++ks) {
            floatx4 a = *(const floatx4*)(hr + 32 * ks + 8 * lg);
            floatx4 b = *(const floatx4*)(hr + 32 * ks + 8 * lg + 4);
            short8 v;
#pragma unroll
            for (int q = 0; q < 4; ++q) { v[q] = (short)f2bf(a[q]); v[4 + q] = (short)f2bf(b[q]); }
            a0[ks] = v;
        }
        const uintx4* p = (const uintx4*)(gx + ((size_t)wv * 64 + lane) * 8);
        uintx4 ga = p[0], gb = p[1];                      // plain C++ load (prologue only)
        floatx4 acc[4];
        acc[0] = (floatx4){bf2f_lo(ga.x), bf2f_hi(ga.x), bf2f_lo(ga.y), bf2f_hi(ga.y)};
        acc[1] = (floatx4){bf2f_lo(ga.z), bf2f_hi(ga.z), bf2f_lo(ga.w), bf2f_hi(ga.w)};
        acc[2] = (floatx4){bf2f_lo(gb.x), bf2f_hi(gb.x), bf2f_lo(gb.y), bf2f_hi(gb.y)};
        acc[3] = (floatx4){bf2f_lo(gb.z), bf2f_hi(gb.z), bf2f_lo(gb.w), bf2f_hi(gb.w)};
        run_mfma(a0, acc);
        float hnew[4];
        gates(acc, hnew);
        tail(0, hnew);                                    // publishes slot 0, polls slot 0, G=gx[1]
    }

    // ---- steps 1..Ss-1
    for (int t = 1; t < Ss; ++t) {
        const u32 want = 0x4000u | ((u32)((t - 1) & 1) << 30);
        const u32* pdc = data + sr * 4096 + (16 * mt + ln) * 128 + 4 * lg;

        int have = 0;
        WAITV(10);                               // A done (pub/out acks ride along; B,G in flight)
        if (dead || chk(dvA, want)) have = 1;
        else {
            WAITV(2);                            // B done; G still in flight
            if (chk(dvB, want)) have = 2;
        }
        if (!have) {
            ISSUE8(dvA, pdc); ISSUE8(dvB, pdc);
            WAITV(8);                            // retires old G + new A
            if (chk(dvA, want)) have = 1;
            while (!have) {
                ISSUE8(dvA, pdc);
                WAITV(8);                        // retires B
                if (chk(dvB, want)) { have = 2; break; }
                ISSUE8(dvB, pdc);
                WAITV(8);                        // retires A
                if (chk(dvA, want)) { have = 1; break; }
                if (++itb >= RETRY_DEAD) { dead = 1; have = 1; }   // latch: free-run to end
            }
        }
        WAITV(0);                                // full drain: G regs (and leftovers) now valid
        if (have == 2) {
#pragma unroll
            for (int ks = 0; ks < 8; ++ks) dvA[ks] = dvB[ks];
        }

        // ---- body (identical math to round 3)
        short8 afr[8];
#pragma unroll
        for (int ks = 0; ks < 8; ++ks) {
            union { uintx4 u; short8 s; } cv;
            cv.u = (uintx4){dvA[ks].x & 0xBFFFBFFFu, dvA[ks].y & 0xBFFFBFFFu,
                            dvA[ks].z & 0xBFFFBFFFu, dvA[ks].w & 0xBFFFBFFFu};
            afr[ks] = cv.s;
        }
        floatx4 acc[4];
        acc[0] = (floatx4){bf2f_lo(g0.x), bf2f_hi(g0.x), bf2f_lo(g0.y), bf2f_hi(g0.y)};
        acc[1] = (floatx4){bf2f_lo(g0.z), bf2f_hi(g0.z), bf2f_lo(g0.w), bf2f_hi(g0.w)};
        acc[2] = (floatx4){bf2f_lo(g1.x), bf2f_hi(g1.x), bf2f_lo(g1.y), bf2f_hi(g1.y)};
        acc[3] = (floatx4){bf2f_lo(g1.z), bf2f_hi(g1.z), bf2f_lo(g1.w), bf2f_hi(g1.w)};
        run_mfma(afr, acc);
        float hnew[4];
        gates(acc, hnew);
        tail(t, hnew);
    }

    float* hfo = out + Bb * Ss * Hh;
    float* cfo = hfo + Bb * Hh;
#pragma unroll
    for (int r = 0; r < 4; ++r) {
        int b = 16 * mt + 4 * lg + r;
        hfo[b * Hh + j] = hl[r];
        cfo[b * Hh + j] = cst[r];
    }
}

extern "C" void kernel_launch(void* const* d_in, const int* in_sizes, int n_in,
                              void* d_out, int out_size, void* d_ws, size_t ws_size,
                              hipStream_t stream) {
    (void)in_sizes; (void)n_in; (void)out_size; (void)ws_size;
    const float* x  = (const float*)d_in[0];
    const float* h0 = (const float*)d_in[1];
    const float* c0 = (const float*)d_in[2];
    const float* Wf = (const float*)d_in[3]; const float* bf = (const float*)d_in[4];
    const float* Wi = (const float*)d_in[5]; const float* bi = (const float*)d_in[6];
    const float* Wc = (const float*)d_in[7]; const float* bc = (const float*)d_in[8];
    const float* Wo = (const float*)d_in[9]; const float* bo = (const float*)d_in[10];

    u32* data = (u32*)((char*)d_ws + DATA_OFF);
    u32* gx   = (u32*)((char*)d_ws + GX_OFF);

    // zero the exchange region: all-zero = "unwritten" under the bit14 validity code
    hipMemsetAsync(d_ws, 0, 65536, stream);

    hipLaunchKernelGGL(lstm_gx_kernel, dim3(2048), dim3(256), 0, stream,
                       x, Wf, bf, Wi, bi, Wc, bc, Wo, bo, gx);
    hipLaunchKernelGGL(lstm_rec11, dim3(8), dim3(256), 0, stream,
                       h0, c0, Wf, Wi, Wc, Wo, (float*)d_out, data, gx);
}

// Round 8
// 7906.985 us; speedup vs baseline: 1.0414x; 1.0414x over previous
//
#include <hip/hip_runtime.h>
#include <hip/hip_bf16.h>

typedef __attribute__((ext_vector_type(8))) short short8;
typedef __attribute__((ext_vector_type(4))) float floatx4;
typedef __attribute__((ext_vector_type(4))) unsigned int uintx4;
typedef unsigned int u32;

#define Bb 32
#define Ss 2048
#define Ii 256
#define Hh 256

// ws layout:
//   [4096, 53248)   data: u32 data[3][32][128] — value-validated h exchange, slot = t%3
//                   word = packed bf16 pair | 0x4000 (written, lo bit14) | parity<<30 (hi bit14)
//                   (|h|<=1.0 => bf16 bit14 always 0 => both bits free; 0xAAAAAAAA and
//                    0x00000000 poison both fail the check)
//   [65536, ...)    gx: bf16 pre-activation fragments (proven layout)
#define DATA_OFF 4096
#define GX_OFF   65536
// container-safety: ONE global timeout budget (~0.1s max extra spin), then dead-latch
#define RETRY_DEAD (1u << 17)

__device__ __forceinline__ unsigned short f2bf(float f) {
    unsigned int u = __float_as_uint(f);
    u += 0x7fffu + ((u >> 16) & 1u);   // RNE
    return (unsigned short)(u >> 16);
}
__device__ __forceinline__ float bf2f_lo(u32 w) { return __uint_as_float(w << 16); }
__device__ __forceinline__ float bf2f_hi(u32 w) { return __uint_as_float(w & 0xffff0000u); }

__device__ __forceinline__ float fast_sigmoid(float x) {
    return __builtin_amdgcn_rcpf(1.0f + __expf(-x));
}
__device__ __forceinline__ float fast_tanh(float x) {
    return 1.0f - 2.0f * __builtin_amdgcn_rcpf(__expf(2.0f * x) + 1.0f);
}

// counted wait + scheduler fence (rule #18): nothing reading asm-loaded regs may
// hoist above this point
#define WAITV(N) do { asm volatile("s_waitcnt vmcnt(" #N ")" ::: "memory"); \
                      __builtin_amdgcn_sched_barrier(0); } while (0)
// stagger delay ~512 cycles (~0.21us): spaces the two in-flight samples in time
#define SLEEP8 asm volatile("s_sleep 8" ::: "memory")

// liveness fence: reads all 16 uintx4 so the register allocator cannot reuse the
// bundles' physical registers anywhere between their asm defs and this point.
// Placed ONLY after a WAITV that guarantees all landings are complete.
#define KEEPALIVE(A, B)                                                      \
    asm volatile("" :: "v"(A[0]), "v"(A[1]), "v"(A[2]), "v"(A[3]),           \
                       "v"(A[4]), "v"(A[5]), "v"(A[6]), "v"(A[7]),           \
                       "v"(B[0]), "v"(B[1]), "v"(B[2]), "v"(B[3]),           \
                       "v"(B[4]), "v"(B[5]), "v"(B[6]), "v"(B[7]))

// issue one 8x dwordx4 poll bundle (sc0 sc1 = MALL-coherent, proven) — NO wait
#define ISSUE8(V, PD)                                                        \
    asm volatile("global_load_dwordx4 %0, %8, off sc0 sc1\n\t"               \
                 "global_load_dwordx4 %1, %8, off offset:64 sc0 sc1\n\t"     \
                 "global_load_dwordx4 %2, %8, off offset:128 sc0 sc1\n\t"    \
                 "global_load_dwordx4 %3, %8, off offset:192 sc0 sc1\n\t"    \
                 "global_load_dwordx4 %4, %8, off offset:256 sc0 sc1\n\t"    \
                 "global_load_dwordx4 %5, %8, off offset:320 sc0 sc1\n\t"    \
                 "global_load_dwordx4 %6, %8, off offset:384 sc0 sc1\n\t"    \
                 "global_load_dwordx4 %7, %8, off offset:448 sc0 sc1"        \
                 : "=&v"(V[0]), "=&v"(V[1]), "=&v"(V[2]), "=&v"(V[3]),       \
                   "=&v"(V[4]), "=&v"(V[5]), "=&v"(V[6]), "=&v"(V[7])        \
                 : "v"(PD) : "memory")

// issue the next step's gx fragment loads (plain cacheable) — NO wait. In-order
// vmcnt retirement: the first WAITV(8) of the next detect retires them for free.
#define ISSUEG(GA, GB, P)                                                    \
    asm volatile("global_load_dwordx4 %0, %2, off\n\t"                       \
                 "global_load_dwordx4 %1, %2, off offset:16"                 \
                 : "=&v"(GA), "=&v"(GB) : "v"(P) : "memory")

// ---------------- Phase 1: gx[t] = x_t @ Wx_all + b_all (byte-identical, proven)
__global__ __launch_bounds__(256, 2)
void lstm_gx_kernel(const float* __restrict__ x,
                    const float* __restrict__ Wf, const float* __restrict__ bfp,
                    const float* __restrict__ Wi, const float* __restrict__ bip,
                    const float* __restrict__ Wc, const float* __restrict__ bcp,
                    const float* __restrict__ Wo, const float* __restrict__ bop,
                    u32* __restrict__ gx)
{
    const int tid = threadIdx.x, wave = tid >> 6, lane = tid & 63;
    const int ln = lane & 15, lg = lane >> 4;
    const int combo = blockIdx.x & 7;
    const int tbase = (blockIdx.x >> 3) * 8;
    const int wg = ((combo & 1) << 2) + wave;
    const int chalf = (combo >> 1) & 1, mtile = combo >> 2;
    const int j0 = wg * 32 + chalf * 16, r0 = mtile * 16;
    const int wv = wg * 4 + chalf * 2 + mtile;

    const float* Wg[4] = {Wf, Wi, Wc, Wo};
    const float* bg[4] = {bfp, bip, bcp, bop};
    float bias[4];
#pragma unroll
    for (int g = 0; g < 4; ++g) bias[g] = bg[g][j0 + ln];

    short8 Bf[4][8];
#pragma unroll
    for (int g = 0; g < 4; ++g)
#pragma unroll
        for (int ks = 0; ks < 8; ++ks) {
            short8 v;
#pragma unroll
            for (int i = 0; i < 8; ++i) {
                int k = 256 + 32 * ks + 8 * lg + i;
                v[i] = (short)f2bf(Wg[g][k * Hh + (j0 + ln)]);
            }
            Bf[g][ks] = v;
        }

    for (int it = 0; it < 8; ++it) {
        int t = tbase + it;
        short8 xf[8];
#pragma unroll
        for (int ks = 0; ks < 8; ++ks) {
            const float* px = x + (r0 + ln) * (Ss * Ii) + t * Ii + 32 * ks + 8 * lg;
            floatx4 a = *(const floatx4*)px;
            floatx4 b = *(const floatx4*)(px + 4);
            short8 v;
#pragma unroll
            for (int q = 0; q < 4; ++q) { v[q] = (short)f2bf(a[q]); v[4 + q] = (short)f2bf(b[q]); }
            xf[ks] = v;
        }
        floatx4 acc[4];
#pragma unroll
        for (int g = 0; g < 4; ++g) acc[g] = (floatx4){0.f, 0.f, 0.f, 0.f};
#pragma unroll
        for (int ks = 0; ks < 8; ++ks)
#pragma unroll
            for (int g = 0; g < 4; ++g)
                acc[g] = __builtin_amdgcn_mfma_f32_16x16x32_bf16(xf[ks], Bf[g][ks], acc[g], 0, 0, 0);

        u32 o[8];
#pragma unroll
        for (int g = 0; g < 4; ++g)
#pragma unroll
            for (int rp = 0; rp < 2; ++rp) {
                float v0 = acc[g][2 * rp] + bias[g];
                float v1 = acc[g][2 * rp + 1] + bias[g];
                o[g * 2 + rp] = (u32)f2bf(v0) | ((u32)f2bf(v1) << 16);
            }
        u32* dst = gx + ((size_t)(t * 32 + wv) * 64 + lane) * 8;
        ((uintx4*)dst)[0] = (uintx4){o[0], o[1], o[2], o[3]};
        ((uintx4*)dst)[1] = (uintx4){o[4], o[5], o[6], o[7]};
    }
}

// ---------------- Phase 2: round-3 protocol + staggered ping-pong sampling.
// Per-step schedule:
//   entry: WAITV(10) retires ONLY the previous loser (queue: loser8,pub4,out4,gx2)
//          KEEPALIVE fences liveness of both bundles past all landings
//   detect: issue A, sleep, issue B; each WAITV(8) exposes the older sample while
//           the newer flies -> sampling period ~0.25us instead of a full RT
//   body:  winner extracted via both-read mask merge (no regalloc reuse of the
//          in-flight loser's registers); loser drains at next entry
__global__ __launch_bounds__(256, 1)
void lstm_rec13(const float* __restrict__ h0,
                const float* __restrict__ c0,
                const float* __restrict__ Wf,
                const float* __restrict__ Wi,
                const float* __restrict__ Wc,
                const float* __restrict__ Wo,
                float* __restrict__ out,
                u32* data, const u32* __restrict__ gx)
{
    const int wg = blockIdx.x;
    const int tid = threadIdx.x;
    const int wave = tid >> 6, lane = tid & 63;
    const int mt = wave & 1, chalf = wave >> 1;   // batch-half, col-block
    const int ln = lane & 15, lg = lane >> 4;
    const int j0 = wg * 32 + chalf * 16;
    const int j = j0 + ln;
    const int wv = wg * 4 + chalf * 2 + mt;       // gx fragment slot (matches writer)

    const float* Wg[4] = {Wf, Wi, Wc, Wo};
    short8 Bfrag[4][8];                            // h-part weights, full K=256
#pragma unroll
    for (int g = 0; g < 4; ++g)
#pragma unroll
        for (int ks = 0; ks < 8; ++ks) {
            short8 v;
#pragma unroll
            for (int i = 0; i < 8; ++i) {
                int k = 32 * ks + 8 * lg + i;
                v[i] = (short)f2bf(Wg[g][k * Hh + j]);
            }
            Bfrag[g][ks] = v;
        }

    float cst[4], hl[4];
#pragma unroll
    for (int r = 0; r < 4; ++r) {
        cst[r] = c0[(16 * mt + 4 * lg + r) * Hh + j];
        hl[r] = 0.0f;
    }

    uintx4 dvA[8], dvB[8];
#pragma unroll
    for (int ks = 0; ks < 8; ++ks) {               // defined values for t=1 KEEPALIVE
        dvA[ks] = (uintx4){0, 0, 0, 0};
        dvB[ks] = (uintx4){0, 0, 0, 0};
    }
    uintx4 g0, g1;
    u32 itb = 0, dead = 0;

    // parity-validity check over one 8-bundle; wave-uniform verdict
    auto chk = [&](const uintx4 v[8], u32 want) -> bool {
        u32 bad = 0;
#pragma unroll
        for (int ks = 0; ks < 8; ++ks) {
            bad |= (v[ks].x & 0x40004000u) ^ want;
            bad |= (v[ks].y & 0x40004000u) ^ want;
            bad |= (v[ks].z & 0x40004000u) ^ want;
            bad |= (v[ks].w & 0x40004000u) ^ want;
        }
        return !__any((int)(bad != 0));
    };

    auto gates = [&](floatx4 (&acc)[4], float (&hnew)[4]) {
#pragma unroll
        for (int r = 0; r < 4; ++r) {
            float fg = fast_sigmoid(acc[0][r]);
            float ig = fast_sigmoid(acc[1][r]);
            float cd = fast_tanh(acc[2][r]);
            float og = fast_sigmoid(acc[3][r]);
            float c  = cst[r] * fg + ig * cd;
            cst[r] = c;
            hnew[r] = og * fast_tanh(c);
            hl[r] = hnew[r];
        }
    };

    auto run_mfma = [&](short8 (&afr)[8], floatx4 (&acc)[4]) {
#pragma unroll
        for (int ks = 0; ks < 8; ++ks)
#pragma unroll
            for (int g = 0; g < 4; ++g)
                acc[g] = __builtin_amdgcn_mfma_f32_16x16x32_bf16(afr[ks], Bfrag[g][ks], acc[g], 0, 0, 0);
    };

    int sr = 0, sw = 0;

    // step tail: publish h_t -> slot sw (fire-and-forget, value-validated), out stores,
    // issue next gx fragment loads. VMEM queue appended per step: pub(4) out(4) gx(2).
    auto tail = [&](int t, const float hnew[4]) {
        const u32 tb = 0x4000u | ((u32)(t & 1) << 30);
        u32 wrd[4];
#pragma unroll
        for (int r = 0; r < 4; ++r) {
            float partner = __shfl_xor(hnew[r], 1);
            wrd[r] = ((u32)f2bf(hnew[r]) | ((u32)f2bf(partner) << 16)) | tb;  // even lanes valid
        }
        u32* pw = data + sw * 4096 + (16 * mt + 4 * lg) * 128 + (j >> 1);
        if ((ln & 1) == 0) {
            asm volatile("global_store_dword %4, %0, off sc0 sc1\n\t"
                         "global_store_dword %4, %1, off offset:512 sc0 sc1\n\t"
                         "global_store_dword %4, %2, off offset:1024 sc0 sc1\n\t"
                         "global_store_dword %4, %3, off offset:1536 sc0 sc1"
                         :: "v"(wrd[0]), "v"(wrd[1]), "v"(wrd[2]), "v"(wrd[3]), "v"(pw)
                         : "memory");
        }
#pragma unroll
        for (int r = 0; r < 4; ++r)
            out[(16 * mt + 4 * lg + r) * (Ss * Hh) + t * Hh + j] = hnew[r];
        int tg = (t + 1 < Ss) ? (t + 1) : (Ss - 1);     // clamp: never read past gx end
        const u32* pg = gx + ((size_t)(tg * 32 + wv) * 64 + lane) * 8;
        ISSUEG(g0, g1, pg);
        sr = sw; sw = (sw == 2) ? 0 : sw + 1;
    };

    // ---- step 0: A-fragments straight from h0 (global, fully available — no exchange)
    {
        short8 a0[8];
        const float* hr = h0 + (16 * mt + ln) * Hh;
#pragma unroll
        for (int ks = 0; ks < 8; ++ks) {
            floatx4 a = *(const floatx4*)(hr + 32 * ks + 8 * lg);
            floatx4 b = *(const floatx4*)(hr + 32 * ks + 8 * lg + 4);
            short8 v;
#pragma unroll
            for (int q = 0; q < 4; ++q) { v[q] = (short)f2bf(a[q]); v[4 + q] = (short)f2bf(b[q]); }
            a0[ks] = v;
        }
        const uintx4* p = (const uintx4*)(gx + ((size_t)wv * 64 + lane) * 8);
        uintx4 ga = p[0], gb = p[1];                      // plain C++ load (prologue only)
        floatx4 acc[4];
        acc[0] = (floatx4){bf2f_lo(ga.x), bf2f_hi(ga.x), bf2f_lo(ga.y), bf2f_hi(ga.y)};
        acc[1] = (floatx4){bf2f_lo(ga.z), bf2f_hi(ga.z), bf2f_lo(ga.w), bf2f_hi(ga.w)};
        acc[2] = (floatx4){bf2f_lo(gb.x), bf2f_hi(gb.x), bf2f_lo(gb.y), bf2f_hi(gb.y)};
        acc[3] = (floatx4){bf2f_lo(gb.z), bf2f_hi(gb.z), bf2f_lo(gb.w), bf2f_hi(gb.w)};
        run_mfma(a0, acc);
        float hnew[4];
        gates(acc, hnew);
        tail(0, hnew);                                    // publish slot 0; gx[1] -> g0,g1
    }

    // ---- steps 1..Ss-1
    for (int t = 1; t < Ss; ++t) {
        const u32 want = 0x4000u | ((u32)((t - 1) & 1) << 30);
        const u32* pd = data + sr * 4096 + (16 * mt + ln) * 128 + 4 * lg;

        // ---- entry drain: queue = [loser(<=8), pub4, out4, gx2]. WAITV(10) retires
        // exactly the loser; tail ops stay in flight. KEEPALIVE then pins both
        // bundles' registers: every landing is complete, no reuse window existed.
        WAITV(10);
        KEEPALIVE(dvA, dvB);

        // ---- staggered ping-pong detect (samples spaced ~0.21us apart)
        int have = 0;
        ISSUE8(dvA, pd);
        SLEEP8;
        ISSUE8(dvB, pd);
        for (;;) {
            WAITV(8);                                // A done (+pub/out/gx); B in flight
            if (dead || chk(dvA, want)) { have = 1; break; }
            SLEEP8;
            ISSUE8(dvA, pd);
            WAITV(8);                                // B done; new A in flight
            if (chk(dvB, want)) { have = 2; break; }
            SLEEP8;
            ISSUE8(dvB, pd);
            if (++itb >= RETRY_DEAD) dead = 1;       // global latch: free-run to end
        }

        // ---- winner extraction: both-read mask merge (reads BOTH arrays so the
        // in-flight loser's registers stay live through the whole body)
        const u32 m = (have == 1) ? 0xFFFFFFFFu : 0u;
        short8 afr[8];
#pragma unroll
        for (int ks = 0; ks < 8; ++ks) {
            union { uintx4 u; short8 s; } cv;
            cv.u.x = ((dvA[ks].x & m) | (dvB[ks].x & ~m)) & 0xBFFFBFFFu;
            cv.u.y = ((dvA[ks].y & m) | (dvB[ks].y & ~m)) & 0xBFFFBFFFu;
            cv.u.z = ((dvA[ks].z & m) | (dvB[ks].z & ~m)) & 0xBFFFBFFFu;
            cv.u.w = ((dvA[ks].w & m) | (dvB[ks].w & ~m)) & 0xBFFFBFFFu;
            afr[ks] = cv.s;
        }

        // ---- body (math identical to round 3); g0,g1 retired by the first WAITV(8)
        floatx4 acc[4];
        acc[0] = (floatx4){bf2f_lo(g0.x), bf2f_hi(g0.x), bf2f_lo(g0.y), bf2f_hi(g0.y)};
        acc[1] = (floatx4){bf2f_lo(g0.z), bf2f_hi(g0.z), bf2f_lo(g0.w), bf2f_hi(g0.w)};
        acc[2] = (floatx4){bf2f_lo(g1.x), bf2f_hi(g1.x), bf2f_lo(g1.y), bf2f_hi(g1.y)};
        acc[3] = (floatx4){bf2f_lo(g1.z), bf2f_hi(g1.z), bf2f_lo(g1.w), bf2f_hi(g1.w)};
        run_mfma(afr, acc);
        float hnew[4];
        gates(acc, hnew);
        tail(t, hnew);
    }

    float* hfo = out + Bb * Ss * Hh;
    float* cfo = hfo + Bb * Hh;
#pragma unroll
    for (int r = 0; r < 4; ++r) {
        int b = 16 * mt + 4 * lg + r;
        hfo[b * Hh + j] = hl[r];
        cfo[b * Hh + j] = cst[r];
    }
}

extern "C" void kernel_launch(void* const* d_in, const int* in_sizes, int n_in,
                              void* d_out, int out_size, void* d_ws, size_t ws_size,
                              hipStream_t stream) {
    (void)in_sizes; (void)n_in; (void)out_size; (void)ws_size;
    const float* x  = (const float*)d_in[0];
    const float* h0 = (const float*)d_in[1];
    const float* c0 = (const float*)d_in[2];
    const float* Wf = (const float*)d_in[3]; const float* bf = (const float*)d_in[4];
    const float* Wi = (const float*)d_in[5]; const float* bi = (const float*)d_in[6];
    const float* Wc = (const float*)d_in[7]; const float* bc = (const float*)d_in[8];
    const float* Wo = (const float*)d_in[9]; const float* bo = (const float*)d_in[10];

    u32* data = (u32*)((char*)d_ws + DATA_OFF);
    u32* gx   = (u32*)((char*)d_ws + GX_OFF);

    // zero the exchange region: all-zero = "unwritten" under the bit14 validity code
    hipMemsetAsync(d_ws, 0, 65536, stream);

    hipLaunchKernelGGL(lstm_gx_kernel, dim3(2048), dim3(256), 0, stream,
                       x, Wf, bf, Wi, bi, Wc, bc, Wo, bo, gx);
    hipLaunchKernelGGL(lstm_rec13, dim3(8), dim3(256), 0, stream,
                       h0, c0, Wf, Wi, Wc, Wo, (float*)d_out, data, gx);
}